// Round 1
// baseline (986.824 us; speedup 1.0000x reference)
//
#include <hip/hip_runtime.h>

// GraphSAGE 2-layer + global mean pool, fp32.
// N=100000 nodes, E=1e6 edges, 64 -> 64 (relu) -> 128 channels, 128 graphs.

#define NODES     100000
#define IN_CH     64
#define HID_CH    64
#define OUT_CH    128
#define N_GRAPHS  128

// ---------------- degree (in-degree over dst) ----------------
__global__ __launch_bounds__(256) void deg_kernel(const int* __restrict__ dst,
                                                  float* __restrict__ deg, int E) {
    int e = blockIdx.x * 256 + threadIdx.x;
    if (e < E) atomicAdd(&deg[dst[e]], 1.0f);
}

// ---------------- edge scatter-add: agg[dst] += feat[src] ----------------
// one wave per edge; lane f handles feature f (64 features)
__global__ __launch_bounds__(256) void scatter_kernel(const float* __restrict__ feat,
                                                      const int* __restrict__ src,
                                                      const int* __restrict__ dst,
                                                      float* __restrict__ agg, int E) {
    int e = blockIdx.x * 4 + (threadIdx.x >> 6);   // wave-uniform
    int f = threadIdx.x & 63;
    if (e < E) {
        int s = src[e];
        int d = dst[e];
        atomicAdd(&agg[(size_t)d * 64 + f], feat[(size_t)s * 64 + f]);
    }
}

// ---------------- per-node transform ----------------
// out[n][o] = (agg[n]/max(deg,1)) . Wl[o] + b[o] + self[n] . Wr[o]   (opt relu)
// Weights staged transposed+padded in LDS; node row broadcast via __shfl.
template <int OUTC, bool RELU>
__global__ __launch_bounds__(256) void transform_kernel(
    const float* __restrict__ self_feat,  // [N,64]
    const float* __restrict__ agg,        // [N,64]
    const float* __restrict__ deg,        // [N]
    const float* __restrict__ Wl,         // [OUTC,64] row-major
    const float* __restrict__ Wr,         // [OUTC,64]
    const float* __restrict__ bias,       // [OUTC]
    float* __restrict__ out,              // [N,OUTC]
    int n_nodes) {
    constexpr int LDW = OUTC + 1;         // pad -> conflict-free
    __shared__ float wl[64 * LDW];
    __shared__ float wr[64 * LDW];
    int tid = threadIdx.x;
    for (int i = tid; i < 64 * OUTC; i += 256) {
        int o = i >> 6, k = i & 63;       // W[o][k]
        wl[k * LDW + o] = Wl[i];          // store transposed: wl[k][o]
        wr[k * LDW + o] = Wr[i];
    }
    __syncthreads();

    int wid = tid >> 6, lane = tid & 63;
    const int NPW = 8;                    // nodes per wave
    int base = blockIdx.x * (4 * NPW) + wid * NPW;
    for (int j = 0; j < NPW; j++) {
        int node = base + j;
        if (node >= n_nodes) break;
        float xv = self_feat[(size_t)node * 64 + lane];
        float av = agg[(size_t)node * 64 + lane];
        float inv = 1.0f / fmaxf(deg[node], 1.0f);
        av *= inv;
        float acc[OUTC / 64];
#pragma unroll
        for (int q = 0; q < OUTC / 64; q++) acc[q] = bias[lane + 64 * q];
#pragma unroll
        for (int k = 0; k < 64; k++) {
            float ak = __shfl(av, k);     // -> v_readlane (k literal after unroll)
            float xk = __shfl(xv, k);
#pragma unroll
            for (int q = 0; q < OUTC / 64; q++) {
                acc[q] += ak * wl[k * LDW + lane + 64 * q]
                        + xk * wr[k * LDW + lane + 64 * q];
            }
        }
#pragma unroll
        for (int q = 0; q < OUTC / 64; q++) {
            float v = acc[q];
            if (RELU) v = fmaxf(v, 0.0f);
            out[(size_t)node * OUTC + lane + 64 * q] = v;
        }
    }
}

// ---------------- segmented mean-pool over sorted batch ----------------
// 128 threads = one per channel; block owns a contiguous node range.
__global__ __launch_bounds__(128) void pool_kernel(const float* __restrict__ feat,   // [N,128]
                                                   const int* __restrict__ batch,
                                                   float* __restrict__ pooled,       // [G,128]
                                                   float* __restrict__ cnt,          // [G]
                                                   int n_nodes, int npb) {
    int o = threadIdx.x;
    int n0 = blockIdx.x * npb;
    if (n0 >= n_nodes) return;
    int n1 = min(n0 + npb, n_nodes);
    int cur = batch[n0];
    float acc = 0.f, c = 0.f;
    for (int n = n0; n < n1; n++) {
        int g = batch[n];
        if (g != cur) {
            atomicAdd(&pooled[cur * OUT_CH + o], acc);
            if (o == 0) atomicAdd(&cnt[cur], c);
            acc = 0.f; c = 0.f; cur = g;
        }
        acc += feat[(size_t)n * OUT_CH + o];
        c += 1.0f;
    }
    atomicAdd(&pooled[cur * OUT_CH + o], acc);
    if (o == 0) atomicAdd(&cnt[cur], c);
}

__global__ __launch_bounds__(256) void finalize_kernel(const float* __restrict__ pooled,
                                                       const float* __restrict__ cnt,
                                                       float* __restrict__ out, int total) {
    int t = blockIdx.x * 256 + threadIdx.x;
    if (t < total) out[t] = pooled[t] / fmaxf(cnt[t >> 7], 1.0f);
}

extern "C" void kernel_launch(void* const* d_in, const int* in_sizes, int n_in,
                              void* d_out, int out_size, void* d_ws, size_t ws_size,
                              hipStream_t stream) {
    const float* x    = (const float*)d_in[0];
    const int*   ei   = (const int*)d_in[1];
    const int*   bat  = (const int*)d_in[2];
    const float* Wl1  = (const float*)d_in[3];
    const float* Wr1  = (const float*)d_in[4];
    const float* b1   = (const float*)d_in[5];
    const float* Wl2  = (const float*)d_in[6];
    const float* Wr2  = (const float*)d_in[7];
    const float* b2   = (const float*)d_in[8];
    float* out = (float*)d_out;

    const int N = in_sizes[0] / IN_CH;        // 100000
    const int E = in_sizes[1] / 2;            // 1000000
    const int* srcp = ei;
    const int* dstp = ei + E;

    // workspace layout (256B aligned)
    char* ws = (char*)d_ws;
    size_t off = 0;
    auto alloc = [&](size_t bytes) { size_t p = off; off += (bytes + 255) & ~255ull; return p; };
    size_t deg_off    = alloc((size_t)N * 4);
    size_t cnt_off    = alloc((size_t)N_GRAPHS * 4);
    size_t pooled_off = alloc((size_t)N_GRAPHS * OUT_CH * 4);
    size_t agg_off    = alloc((size_t)N * 64 * 4);
    size_t h_off      = alloc((size_t)N * 64 * 4);
    size_t out2_off   = alloc((size_t)N * OUT_CH * 4);
    (void)ws_size;

    float* deg    = (float*)(ws + deg_off);
    float* cnt    = (float*)(ws + cnt_off);
    float* pooled = (float*)(ws + pooled_off);
    float* agg    = (float*)(ws + agg_off);
    float* h      = (float*)(ws + h_off);
    float* out2   = (float*)(ws + out2_off);

    // zero deg+cnt+pooled+agg in one contiguous memset
    hipMemsetAsync(ws, 0, agg_off + (size_t)N * 64 * 4, stream);

    deg_kernel<<<(E + 255) / 256, 256, 0, stream>>>(dstp, deg, E);

    // ---- conv1 ----
    scatter_kernel<<<(E + 3) / 4, 256, 0, stream>>>(x, srcp, dstp, agg, E);
    transform_kernel<64, true><<<(N + 31) / 32, 256, 0, stream>>>(
        x, agg, deg, Wl1, Wr1, b1, h, N);

    // ---- conv2 ----
    hipMemsetAsync(agg, 0, (size_t)N * 64 * 4, stream);
    scatter_kernel<<<(E + 3) / 4, 256, 0, stream>>>(h, srcp, dstp, agg, E);
    transform_kernel<128, false><<<(N + 31) / 32, 256, 0, stream>>>(
        h, agg, deg, Wl2, Wr2, b2, out2, N);

    // ---- global mean pool ----
    const int npb = 128;
    pool_kernel<<<(N + npb - 1) / npb, 128, 0, stream>>>(out2, bat, pooled, cnt, N, npb);
    finalize_kernel<<<(N_GRAPHS * OUT_CH + 255) / 256, 256, 0, stream>>>(
        pooled, cnt, out, N_GRAPHS * OUT_CH);
}

// Round 2
// 563.220 us; speedup vs baseline: 1.7521x; 1.7521x over previous
//
#include <hip/hip_runtime.h>

// GraphSAGE 2-layer + global mean pool, fp32.
// N=100000 nodes, E=1e6 edges, 64 -> 64 (relu) -> 128 channels, 128 graphs.

#define IN_CH     64
#define HID_CH    64
#define OUT_CH    128
#define N_GRAPHS  128

__device__ __forceinline__ float bcast(float v, int k) {
    return __int_as_float(__builtin_amdgcn_readlane(__float_as_int(v), k));
}

// ---------------- degree (in-degree over dst), int ----------------
__global__ __launch_bounds__(256) void deg_kernel(const int* __restrict__ dst,
                                                  int* __restrict__ degi, int E) {
    int e = blockIdx.x * 256 + threadIdx.x;
    if (e < E) atomicAdd(&degi[dst[e]], 1);
}

// ---------------- block-wise scan of degi -> rowptr (partial) ----------------
__global__ __launch_bounds__(1024) void scan_block_kernel(const int* __restrict__ degi,
                                                          int* __restrict__ rowptr,
                                                          int* __restrict__ bsum, int N) {
    __shared__ int tmp[1024];
    int tid = threadIdx.x;
    int i = blockIdx.x * 1024 + tid;
    int v = (i < N) ? degi[i] : 0;
    int val = v;
    tmp[tid] = v;
    __syncthreads();
    for (int off = 1; off < 1024; off <<= 1) {
        int t = (tid >= off) ? tmp[tid - off] : 0;
        __syncthreads();
        val += t;
        tmp[tid] = val;
        __syncthreads();
    }
    if (i < N) rowptr[i] = val - v;            // exclusive within block
    if (tid == 1023) bsum[blockIdx.x] = val;   // block total
}

__global__ void scan_sums_kernel(int* __restrict__ bsum, int nb) {
    if (threadIdx.x == 0 && blockIdx.x == 0) {
        int acc = 0;
        for (int b = 0; b < nb; b++) { int t = bsum[b]; bsum[b] = acc; acc += t; }
    }
}

__global__ __launch_bounds__(256) void scan_add_kernel(const int* __restrict__ bsum,
                                                       int* __restrict__ rowptr,
                                                       int* __restrict__ cursor,
                                                       int N, int E) {
    int i = blockIdx.x * 256 + threadIdx.x;
    if (i < N) {
        int r = rowptr[i] + bsum[i >> 10];
        rowptr[i] = r;
        cursor[i] = r;
    }
    if (i == N) rowptr[N] = E;
}

// ---------------- counting-sort fill: csr_src per dst ----------------
__global__ __launch_bounds__(256) void fill_kernel(const int* __restrict__ src,
                                                   const int* __restrict__ dst,
                                                   int* __restrict__ cursor,
                                                   int* __restrict__ csr, int E) {
    int e = blockIdx.x * 256 + threadIdx.x;
    if (e < E) {
        int pos = atomicAdd(&cursor[dst[e]], 1);
        csr[pos] = src[e];
    }
}

// ---------------- gather aggregation with mean folded in ----------------
// one wave per node; lane f handles feature f
__global__ __launch_bounds__(256) void agg_kernel(const float* __restrict__ feat,
                                                  const int* __restrict__ csr,
                                                  const int* __restrict__ rowptr,
                                                  float* __restrict__ agg, int N) {
    int node = blockIdx.x * 4 + (threadIdx.x >> 6);
    int f = threadIdx.x & 63;
    if (node >= N) return;
    int e0 = rowptr[node], e1 = rowptr[node + 1];
    float acc = 0.f;
    for (int e = e0; e < e1; e++) {
        int s = csr[e];
        acc += feat[(size_t)s * 64 + f];
    }
    agg[(size_t)node * 64 + f] = acc * (1.0f / fmaxf((float)(e1 - e0), 1.0f));
}

// ---------------- fallback: atomic edge scatter (raw sums) ----------------
__global__ __launch_bounds__(256) void scatter_kernel(const float* __restrict__ feat,
                                                      const int* __restrict__ src,
                                                      const int* __restrict__ dst,
                                                      float* __restrict__ agg, int E) {
    int e = blockIdx.x * 4 + (threadIdx.x >> 6);
    int f = threadIdx.x & 63;
    if (e < E) {
        int s = src[e];
        int d = dst[e];
        atomicAdd(&agg[(size_t)d * 64 + f], feat[(size_t)s * 64 + f]);
    }
}

// ---------------- per-node transform ----------------
// out[n][oc] = agg_mean[n].Wl[oc] + b[oc] + self[n].Wr[oc]  (opt relu)
// Wave register-blocks NB nodes in the k-loop; weight LDS reads amortized 16x;
// node features broadcast via v_readlane (SGPR operand -> FMA).
template <int OUTC, bool RELU>
__global__ __launch_bounds__(256, 2) void transform_kernel(
    const float* __restrict__ self_feat,  // [N,64]
    const float* __restrict__ agg,        // [N,64] (mean if degi==nullptr, raw sum otherwise)
    const int*   __restrict__ degi,       // nullptr -> already averaged
    const float* __restrict__ Wl,         // [OUTC,64] row-major
    const float* __restrict__ Wr,         // [OUTC,64]
    const float* __restrict__ bias,       // [OUTC]
    float* __restrict__ out,              // [N,OUTC]
    int n_nodes, int n_tiles) {
    constexpr int Q   = OUTC / 64;        // outputs per lane
    constexpr int LDW = OUTC + 2;         // pad 2: conflict-light writes, 8B-aligned float2 reads
    constexpr int NB  = 16;               // nodes per wave
    __shared__ float wlds[64 * LDW];
    __shared__ float wrds[64 * LDW];
    const int tid = threadIdx.x;
    for (int i = tid; i < 64 * OUTC; i += 256) {
        int oc = i >> 6, k = i & 63;      // W[oc][k], coalesced global read
        wlds[k * LDW + oc] = Wl[i];
        wrds[k * LDW + oc] = Wr[i];
    }
    const int wid = tid >> 6, lane = tid & 63;
    float bv[Q];
#pragma unroll
    for (int q = 0; q < Q; q++) bv[q] = bias[lane * Q + q];
    __syncthreads();

    for (int tile = blockIdx.x; tile < n_tiles; tile += gridDim.x) {
        const int base = tile * (4 * NB) + wid * NB;
        float av[NB], xv[NB];
#pragma unroll
        for (int j = 0; j < NB; j++) {
            int node = base + j;
            bool ok = node < n_nodes;
            size_t o64 = (size_t)node * 64 + lane;
            av[j] = ok ? agg[o64] : 0.f;
            xv[j] = ok ? self_feat[o64] : 0.f;
        }
        if (degi) {
#pragma unroll
            for (int j = 0; j < NB; j++) {
                int node = base + j;
                float d = (node < n_nodes) ? (float)degi[node] : 1.f;
                av[j] *= 1.0f / fmaxf(d, 1.f);
            }
        }
        float acc[NB][Q];
#pragma unroll
        for (int j = 0; j < NB; j++)
#pragma unroll
            for (int q = 0; q < Q; q++) acc[j][q] = 0.f;

#pragma unroll 2
        for (int k = 0; k < 64; k++) {
            float wlv[Q], wrv[Q];
#pragma unroll
            for (int q = 0; q < Q; q++) {
                wlv[q] = wlds[k * LDW + lane * Q + q];
                wrv[q] = wrds[k * LDW + lane * Q + q];
            }
#pragma unroll
            for (int j = 0; j < NB; j++) {
                float ak = bcast(av[j], k);
                float xk = bcast(xv[j], k);
#pragma unroll
                for (int q = 0; q < Q; q++)
                    acc[j][q] += ak * wlv[q] + xk * wrv[q];
            }
        }
#pragma unroll
        for (int j = 0; j < NB; j++) {
            int node = base + j;
            if (node < n_nodes) {
#pragma unroll
                for (int q = 0; q < Q; q++) {
                    float v = acc[j][q] + bv[q];
                    if (RELU) v = fmaxf(v, 0.f);
                    out[(size_t)node * OUTC + lane * Q + q] = v;
                }
            }
        }
    }
}

// ---------------- segmented mean-pool over sorted batch ----------------
__global__ __launch_bounds__(128) void pool_kernel(const float* __restrict__ feat,   // [N,128]
                                                   const int* __restrict__ batch,
                                                   float* __restrict__ pooled,       // [G,128]
                                                   float* __restrict__ cnt,          // [G]
                                                   int n_nodes, int npb) {
    int o = threadIdx.x;
    int n0 = blockIdx.x * npb;
    if (n0 >= n_nodes) return;
    int n1 = min(n0 + npb, n_nodes);
    int cur = batch[n0];
    float acc = 0.f, c = 0.f;
    for (int n = n0; n < n1; n++) {
        int g = batch[n];
        if (g != cur) {
            atomicAdd(&pooled[cur * OUT_CH + o], acc);
            if (o == 0) atomicAdd(&cnt[cur], c);
            acc = 0.f; c = 0.f; cur = g;
        }
        acc += feat[(size_t)n * OUT_CH + o];
        c += 1.0f;
    }
    atomicAdd(&pooled[cur * OUT_CH + o], acc);
    if (o == 0) atomicAdd(&cnt[cur], c);
}

__global__ __launch_bounds__(256) void finalize_kernel(const float* __restrict__ pooled,
                                                       const float* __restrict__ cnt,
                                                       float* __restrict__ out, int total) {
    int t = blockIdx.x * 256 + threadIdx.x;
    if (t < total) out[t] = pooled[t] / fmaxf(cnt[t >> 7], 1.0f);
}

extern "C" void kernel_launch(void* const* d_in, const int* in_sizes, int n_in,
                              void* d_out, int out_size, void* d_ws, size_t ws_size,
                              hipStream_t stream) {
    const float* x    = (const float*)d_in[0];
    const int*   ei   = (const int*)d_in[1];
    const int*   bat  = (const int*)d_in[2];
    const float* Wl1  = (const float*)d_in[3];
    const float* Wr1  = (const float*)d_in[4];
    const float* b1   = (const float*)d_in[5];
    const float* Wl2  = (const float*)d_in[6];
    const float* Wr2  = (const float*)d_in[7];
    const float* b2   = (const float*)d_in[8];
    float* out = (float*)d_out;

    const int N = in_sizes[0] / IN_CH;        // 100000
    const int E = in_sizes[1] / 2;            // 1000000
    const int* srcp = ei;
    const int* dstp = ei + E;

    // workspace layout (256B aligned)
    char* ws = (char*)d_ws;
    size_t off = 0;
    auto alloc = [&](size_t bytes) { size_t p = off; off += (bytes + 255) & ~255ull; return p; };
    size_t degi_off   = alloc((size_t)N * 4);              // zeroed; doubles as cursor in CSR path? no: separate below
    size_t cnt_off    = alloc((size_t)N_GRAPHS * 4);
    size_t pooled_off = alloc((size_t)N_GRAPHS * OUT_CH * 4);
    size_t zero_base_end = off;                            // memset range for CSR path
    size_t agg_off    = alloc((size_t)N * 64 * 4);
    size_t zero_fb_end = off;                              // memset range for fallback path
    size_t h_off      = alloc((size_t)N * 64 * 4);
    size_t out2_off   = alloc((size_t)N * OUT_CH * 4);
    size_t fb_total   = off;                               // fallback footprint (== round-1 size)
    size_t rowptr_off = alloc((size_t)(N + 1) * 4);
    size_t bsum_off   = alloc(1024 * 4);
    size_t csr_off    = alloc((size_t)E * 4);
    size_t csr_total  = off;

    int*   degi   = (int*)(ws + degi_off);
    float* cnt    = (float*)(ws + cnt_off);
    float* pooled = (float*)(ws + pooled_off);
    float* agg    = (float*)(ws + agg_off);
    float* h      = (float*)(ws + h_off);
    float* out2   = (float*)(ws + out2_off);
    int*   rowptr = (int*)(ws + rowptr_off);
    int*   bsum   = (int*)(ws + bsum_off);
    int*   csr    = (int*)(ws + csr_off);
    int*   cursor = degi;  // reused in CSR path (degrees not needed after scan)

    const bool use_csr = (ws_size >= csr_total);
    const int n_tiles = (N + 63) / 64;

    if (use_csr) {
        hipMemsetAsync(ws, 0, zero_base_end, stream);  // degi, cnt, pooled
        deg_kernel<<<(E + 255) / 256, 256, 0, stream>>>(dstp, degi, E);

        const int nb = (N + 1023) / 1024;
        scan_block_kernel<<<nb, 1024, 0, stream>>>(degi, rowptr, bsum, N);
        scan_sums_kernel<<<1, 64, 0, stream>>>(bsum, nb);
        scan_add_kernel<<<(N + 256) / 256, 256, 0, stream>>>(bsum, rowptr, cursor, N, E);
        fill_kernel<<<(E + 255) / 256, 256, 0, stream>>>(srcp, dstp, cursor, csr, E);

        // ---- conv1 ----
        agg_kernel<<<(N + 3) / 4, 256, 0, stream>>>(x, csr, rowptr, agg, N);
        transform_kernel<64, true><<<782, 256, 0, stream>>>(
            x, agg, nullptr, Wl1, Wr1, b1, h, N, n_tiles);
        // ---- conv2 ----
        agg_kernel<<<(N + 3) / 4, 256, 0, stream>>>(h, csr, rowptr, agg, N);
        transform_kernel<128, false><<<512, 256, 0, stream>>>(
            h, agg, nullptr, Wl2, Wr2, b2, out2, N, n_tiles);
    } else {
        // fallback: atomic scatter path (fits in round-1 footprint)
        hipMemsetAsync(ws, 0, zero_fb_end, stream);    // degi, cnt, pooled, agg
        deg_kernel<<<(E + 255) / 256, 256, 0, stream>>>(dstp, degi, E);
        // ---- conv1 ----
        scatter_kernel<<<(E + 3) / 4, 256, 0, stream>>>(x, srcp, dstp, agg, E);
        transform_kernel<64, true><<<782, 256, 0, stream>>>(
            x, agg, degi, Wl1, Wr1, b1, h, N, n_tiles);
        // ---- conv2 ----
        hipMemsetAsync(agg, 0, (size_t)N * 64 * 4, stream);
        scatter_kernel<<<(E + 3) / 4, 256, 0, stream>>>(h, srcp, dstp, agg, E);
        transform_kernel<128, false><<<512, 256, 0, stream>>>(
            h, agg, degi, Wl2, Wr2, b2, out2, N, n_tiles);
    }

    // ---- global mean pool ----
    const int npb = 128;
    pool_kernel<<<(N + npb - 1) / npb, 128, 0, stream>>>(out2, bat, pooled, cnt, N, npb);
    finalize_kernel<<<(N_GRAPHS * OUT_CH + 255) / 256, 256, 0, stream>>>(
        pooled, cnt, out, N_GRAPHS * OUT_CH);
    (void)ws_size;
}

// Round 3
// 508.768 us; speedup vs baseline: 1.9396x; 1.1070x over previous
//
#include <hip/hip_runtime.h>

// GraphSAGE 2-layer + global mean pool.
// N=100000 nodes, E=1e6 edges, 64 -> 64 (relu) -> 128 channels, 128 graphs.
// Pipeline: CSR build -> fused {gather-mean + MFMA transform} per conv (bf16
// inputs, f32 accumulate) -> segmented mean pool.

#define IN_CH     64
#define OUT_CH    128
#define N_GRAPHS  128

typedef __attribute__((ext_vector_type(8))) short bf16x8;   // 8 bf16 = 4 VGPR
typedef __attribute__((ext_vector_type(4))) float f32x4;

__device__ __forceinline__ unsigned short f2b(float f) {    // RNE float->bf16
    unsigned int u = __float_as_uint(f);
    return (unsigned short)((u + 0x7FFFu + ((u >> 16) & 1u)) >> 16);
}
__device__ __forceinline__ float b2f(unsigned short h) {
    return __uint_as_float(((unsigned int)h) << 16);
}

// ---------------- x -> bf16 ----------------
__global__ __launch_bounds__(256) void convert_kernel(const float* __restrict__ in,
                                                      unsigned short* __restrict__ out,
                                                      int n4) {
    int i = blockIdx.x * 256 + threadIdx.x;
    if (i < n4) {
        float4 v = ((const float4*)in)[i];
        ushort4 o;
        o.x = f2b(v.x); o.y = f2b(v.y); o.z = f2b(v.z); o.w = f2b(v.w);
        ((ushort4*)out)[i] = o;
    }
}

// ---------------- weight pack: wc[oc][k] = k<64 ? Wl[oc][k] : Wr[oc][k-64] ----------------
__global__ __launch_bounds__(256) void wprep_kernel(const float* __restrict__ Wl1,
                                                    const float* __restrict__ Wr1,
                                                    const float* __restrict__ Wl2,
                                                    const float* __restrict__ Wr2,
                                                    unsigned short* __restrict__ wc1,
                                                    unsigned short* __restrict__ wc2) {
    int i = blockIdx.x * 256 + threadIdx.x;
    if (i < 64 * 128) {
        int oc = i >> 7, k = i & 127;
        float v = (k < 64) ? Wl1[oc * 64 + k] : Wr1[oc * 64 + k - 64];
        wc1[i] = f2b(v);
    } else if (i < 64 * 128 + 128 * 128) {
        int j = i - 64 * 128;
        int oc = j >> 7, k = j & 127;
        float v = (k < 64) ? Wl2[oc * 64 + k] : Wr2[oc * 64 + k - 64];
        wc2[j] = f2b(v);
    }
}

// ---------------- CSR build ----------------
__global__ __launch_bounds__(256) void deg_kernel(const int* __restrict__ dst,
                                                  int* __restrict__ degi, int E) {
    int e = blockIdx.x * 256 + threadIdx.x;
    if (e < E) atomicAdd(&degi[dst[e]], 1);
}

__global__ __launch_bounds__(1024) void scan_block_kernel(const int* __restrict__ degi,
                                                          int* __restrict__ rowptr,
                                                          int* __restrict__ bsum, int N) {
    __shared__ int tmp[1024];
    int tid = threadIdx.x;
    int i = blockIdx.x * 1024 + tid;
    int v = (i < N) ? degi[i] : 0;
    int val = v;
    tmp[tid] = v;
    __syncthreads();
    for (int off = 1; off < 1024; off <<= 1) {
        int t = (tid >= off) ? tmp[tid - off] : 0;
        __syncthreads();
        val += t;
        tmp[tid] = val;
        __syncthreads();
    }
    if (i < N) rowptr[i] = val - v;            // exclusive within block
    if (tid == 1023) bsum[blockIdx.x] = val;   // block total
}

// parallel scan of <=128 block sums (was a serial single-thread loop)
__global__ __launch_bounds__(128) void scan_sums_kernel(int* __restrict__ bsum, int nb) {
    __shared__ int t[128];
    int tid = threadIdx.x;
    int v = (tid < nb) ? bsum[tid] : 0;
    int val = v;
    t[tid] = val;
    __syncthreads();
    for (int o = 1; o < 128; o <<= 1) {
        int add = (tid >= o) ? t[tid - o] : 0;
        __syncthreads();
        val += add;
        t[tid] = val;
        __syncthreads();
    }
    if (tid < nb) bsum[tid] = val - v;         // exclusive block offsets
}

__global__ __launch_bounds__(256) void scan_add_kernel(const int* __restrict__ bsum,
                                                       int* __restrict__ rowptr,
                                                       int* __restrict__ cursor,
                                                       int N, int E) {
    int i = blockIdx.x * 256 + threadIdx.x;
    if (i < N) {
        int r = rowptr[i] + bsum[i >> 10];
        rowptr[i] = r;
        cursor[i] = r;
    }
    if (i == N) rowptr[N] = E;
}

__global__ __launch_bounds__(256) void fill_kernel(const int* __restrict__ src,
                                                   const int* __restrict__ dst,
                                                   int* __restrict__ cursor,
                                                   int* __restrict__ csr, int E) {
    int e = blockIdx.x * 256 + threadIdx.x;
    if (e < E) {
        int pos = atomicAdd(&cursor[dst[e]], 1);
        csr[pos] = src[e];
    }
}

// ---------------- fused SAGE conv: gather-mean + MFMA transform ----------------
// Block = 64 nodes, 4 waves (wave w owns nodes w*16..w*16+15 = its MFMA m-tile).
// K = 128: k<64 = mean-aggregated neighbors (LDS tile), k>=64 = self features
// (A-frags loaded straight from global). B = wc[oc][k] staged in padded LDS.
template <int OUTC, bool RELU, bool OUT_BF16>
__global__ __launch_bounds__(256) void sage_kernel(
    const unsigned short* __restrict__ featb,  // [N,64] bf16
    const int* __restrict__ csr,
    const int* __restrict__ rowptr,
    const unsigned short* __restrict__ wc,     // [OUTC,128] bf16
    const float* __restrict__ bias,            // [OUTC] f32
    void* __restrict__ outp,                   // bf16 [N,OUTC] or f32 [N,OUTC]
    int N) {
    constexpr int KP = 72;                     // 144B row = 9 x 16B slots -> 2-way max
    constexpr int WP = 136;                    // 272B row = 17 x 16B slots
    __shared__ unsigned short feat[64 * KP];
    __shared__ unsigned short wt[OUTC * WP];

    const int tid = threadIdx.x, lane = tid & 63, w = tid >> 6;

    // stage weights, 16B chunks, coalesced
    for (int c = tid; c < OUTC * 16; c += 256) {
        int oc = c >> 4, k8 = (c & 15) * 8;
        *reinterpret_cast<uint4*>(&wt[oc * WP + k8]) =
            *reinterpret_cast<const uint4*>(&wc[oc * 128 + k8]);
    }

    // gather-mean: wave handles its 16 nodes; lane = feature column
    const int base = blockIdx.x * 64 + w * 16;
    for (int j = 0; j < 16; j++) {
        int node = base + j;
        int e0 = 0, e1 = 0;
        if (node < N) { e0 = rowptr[node]; e1 = rowptr[node + 1]; }
        float a0 = 0.f, a1 = 0.f;
        int e = e0;
        for (; e + 1 < e1; e += 2) {           // 2-deep for memory-level parallelism
            int s0 = csr[e], s1 = csr[e + 1];
            a0 += b2f(featb[(size_t)s0 * 64 + lane]);
            a1 += b2f(featb[(size_t)s1 * 64 + lane]);
        }
        if (e < e1) a0 += b2f(featb[(size_t)csr[e] * 64 + lane]);
        float m = (a0 + a1) * (1.0f / fmaxf((float)(e1 - e0), 1.0f));
        feat[(w * 16 + j) * KP + lane] = f2b(m);
    }
    __syncthreads();

    // MFMA phase
    const int hl = lane & 15, sg = lane >> 4;
    bf16x8 a[4];
    a[0] = *reinterpret_cast<const bf16x8*>(&feat[(w * 16 + hl) * KP + sg * 8]);
    a[1] = *reinterpret_cast<const bf16x8*>(&feat[(w * 16 + hl) * KP + 32 + sg * 8]);
    int nclamp = min(base + hl, N - 1);
    const unsigned short* srow = &featb[(size_t)nclamp * 64];
    a[2] = *reinterpret_cast<const bf16x8*>(&srow[sg * 8]);
    a[3] = *reinterpret_cast<const bf16x8*>(&srow[32 + sg * 8]);

    constexpr int NT = OUTC / 16;
#pragma unroll
    for (int nt = 0; nt < NT; nt++) {
        f32x4 acc = {0.f, 0.f, 0.f, 0.f};
#pragma unroll
        for (int ks = 0; ks < 4; ks++) {
            bf16x8 b = *reinterpret_cast<const bf16x8*>(
                &wt[(nt * 16 + hl) * WP + ks * 32 + sg * 8]);
            acc = __builtin_amdgcn_mfma_f32_16x16x32_bf16(a[ks], b, acc, 0, 0, 0);
        }
        float bv = bias[nt * 16 + hl];
#pragma unroll
        for (int r = 0; r < 4; r++) {
            int node = base + sg * 4 + r;      // D row = (lane>>4)*4 + r
            if (node < N) {
                float v = acc[r] + bv;
                if (RELU) v = fmaxf(v, 0.f);
                int oc = nt * 16 + hl;         // D col = lane&15
                if (OUT_BF16)
                    ((unsigned short*)outp)[(size_t)node * OUTC + oc] = f2b(v);
                else
                    ((float*)outp)[(size_t)node * OUTC + oc] = v;
            }
        }
    }
}

// ---------------- segmented mean-pool over sorted batch ----------------
__global__ __launch_bounds__(128) void pool_kernel(const float* __restrict__ feat,   // [N,128]
                                                   const int* __restrict__ batch,
                                                   float* __restrict__ pooled,       // [G,128]
                                                   float* __restrict__ cnt,          // [G]
                                                   int n_nodes, int npb) {
    int o = threadIdx.x;
    int n0 = blockIdx.x * npb;
    if (n0 >= n_nodes) return;
    int n1 = min(n0 + npb, n_nodes);
    int cur = batch[n0];
    float acc = 0.f, c = 0.f;
    for (int n = n0; n < n1; n++) {
        int g = batch[n];
        if (g != cur) {
            atomicAdd(&pooled[cur * OUT_CH + o], acc);
            if (o == 0) atomicAdd(&cnt[cur], c);
            acc = 0.f; c = 0.f; cur = g;
        }
        acc += feat[(size_t)n * OUT_CH + o];
        c += 1.0f;
    }
    atomicAdd(&pooled[cur * OUT_CH + o], acc);
    if (o == 0) atomicAdd(&cnt[cur], c);
}

__global__ __launch_bounds__(256) void finalize_kernel(const float* __restrict__ pooled,
                                                       const float* __restrict__ cnt,
                                                       float* __restrict__ out, int total) {
    int t = blockIdx.x * 256 + threadIdx.x;
    if (t < total) out[t] = pooled[t] / fmaxf(cnt[t >> 7], 1.0f);
}

extern "C" void kernel_launch(void* const* d_in, const int* in_sizes, int n_in,
                              void* d_out, int out_size, void* d_ws, size_t ws_size,
                              hipStream_t stream) {
    const float* x    = (const float*)d_in[0];
    const int*   ei   = (const int*)d_in[1];
    const int*   bat  = (const int*)d_in[2];
    const float* Wl1  = (const float*)d_in[3];
    const float* Wr1  = (const float*)d_in[4];
    const float* b1   = (const float*)d_in[5];
    const float* Wl2  = (const float*)d_in[6];
    const float* Wr2  = (const float*)d_in[7];
    const float* b2   = (const float*)d_in[8];
    float* out = (float*)d_out;

    const int N = in_sizes[0] / IN_CH;        // 100000
    const int E = in_sizes[1] / 2;            // 1000000
    const int* srcp = ei;
    const int* dstp = ei + E;

    // workspace layout (256B aligned); total ~82 MB (round-1 proved >=103 MB usable)
    char* ws = (char*)d_ws;
    size_t off = 0;
    auto alloc = [&](size_t bytes) { size_t p = off; off += (bytes + 255) & ~255ull; return p; };
    size_t degi_off   = alloc((size_t)N * 4);               // zeroed (atomics); reused as cursor
    size_t cnt_off    = alloc((size_t)N_GRAPHS * 4);        // zeroed
    size_t pooled_off = alloc((size_t)N_GRAPHS * OUT_CH * 4); // zeroed
    size_t zero_end   = off;
    size_t xb_off     = alloc((size_t)N * 64 * 2);          // x in bf16
    size_t hb_off     = alloc((size_t)N * 64 * 2);          // h in bf16
    size_t out2_off   = alloc((size_t)N * OUT_CH * 4);      // conv2 out f32
    size_t rowptr_off = alloc((size_t)(N + 1) * 4);
    size_t bsum_off   = alloc(1024 * 4);
    size_t csr_off    = alloc((size_t)E * 4);
    size_t wc1_off    = alloc((size_t)64 * 128 * 2);
    size_t wc2_off    = alloc((size_t)128 * 128 * 2);
    (void)ws_size;

    int*            degi   = (int*)(ws + degi_off);
    float*          cnt    = (float*)(ws + cnt_off);
    float*          pooled = (float*)(ws + pooled_off);
    unsigned short* xb     = (unsigned short*)(ws + xb_off);
    unsigned short* hb     = (unsigned short*)(ws + hb_off);
    float*          out2   = (float*)(ws + out2_off);
    int*            rowptr = (int*)(ws + rowptr_off);
    int*            bsum   = (int*)(ws + bsum_off);
    int*            csr    = (int*)(ws + csr_off);
    unsigned short* wc1    = (unsigned short*)(ws + wc1_off);
    unsigned short* wc2    = (unsigned short*)(ws + wc2_off);
    int*            cursor = degi;   // degrees not needed after scan

    hipMemsetAsync(ws, 0, zero_end, stream);

    // prep: x->bf16, packed bf16 weights
    int n4 = N * 64 / 4;
    convert_kernel<<<(n4 + 255) / 256, 256, 0, stream>>>(x, xb, n4);
    wprep_kernel<<<(24576 + 255) / 256, 256, 0, stream>>>(Wl1, Wr1, Wl2, Wr2, wc1, wc2);

    // CSR build
    deg_kernel<<<(E + 255) / 256, 256, 0, stream>>>(dstp, degi, E);
    const int nb = (N + 1023) / 1024;
    scan_block_kernel<<<nb, 1024, 0, stream>>>(degi, rowptr, bsum, N);
    scan_sums_kernel<<<1, 128, 0, stream>>>(bsum, nb);
    scan_add_kernel<<<(N + 256) / 256, 256, 0, stream>>>(bsum, rowptr, cursor, N, E);
    fill_kernel<<<(E + 255) / 256, 256, 0, stream>>>(srcp, dstp, cursor, csr, E);

    // fused convs
    const int nblk = (N + 63) / 64;
    sage_kernel<64, true, true><<<nblk, 256, 0, stream>>>(xb, csr, rowptr, wc1, b1, hb, N);
    sage_kernel<128, false, false><<<nblk, 256, 0, stream>>>(hb, csr, rowptr, wc2, b2, out2, N);

    // global mean pool
    const int npb = 64;
    pool_kernel<<<(N + npb - 1) / npb, 128, 0, stream>>>(out2, bat, pooled, cnt, N, npb);
    finalize_kernel<<<(N_GRAPHS * OUT_CH + 255) / 256, 256, 0, stream>>>(
        pooled, cnt, out, N_GRAPHS * OUT_CH);
}

// Round 4
// 335.494 us; speedup vs baseline: 2.9414x; 1.5165x over previous
//
#include <hip/hip_runtime.h>

// GraphSAGE 2-layer + global mean pool.
// N=100000 nodes, E=1e6 edges, 64 -> 64 (relu) -> 128 channels, 128 graphs.
// Pipeline: CSR build -> fused {4-edge-parallel gather-mean + MFMA transform}
// per conv (bf16 inputs, f32 accumulate) -> segmented mean pool.

#define IN_CH     64
#define OUT_CH    128
#define N_GRAPHS  128

typedef __attribute__((ext_vector_type(8))) short bf16x8;   // 8 bf16 = 4 VGPR
typedef __attribute__((ext_vector_type(4))) float f32x4;

__device__ __forceinline__ unsigned short f2b(float f) {    // RNE float->bf16
    unsigned int u = __float_as_uint(f);
    return (unsigned short)((u + 0x7FFFu + ((u >> 16) & 1u)) >> 16);
}
__device__ __forceinline__ float b2f(unsigned short h) {
    return __uint_as_float(((unsigned int)h) << 16);
}

// ---------------- x -> bf16 ----------------
__global__ __launch_bounds__(256) void convert_kernel(const float* __restrict__ in,
                                                      unsigned short* __restrict__ out,
                                                      int n4) {
    int i = blockIdx.x * 256 + threadIdx.x;
    if (i < n4) {
        float4 v = ((const float4*)in)[i];
        ushort4 o;
        o.x = f2b(v.x); o.y = f2b(v.y); o.z = f2b(v.z); o.w = f2b(v.w);
        ((ushort4*)out)[i] = o;
    }
}

// ---------------- weight pack: wc[oc][k] = k<64 ? Wl[oc][k] : Wr[oc][k-64] ----------------
__global__ __launch_bounds__(256) void wprep_kernel(const float* __restrict__ Wl1,
                                                    const float* __restrict__ Wr1,
                                                    const float* __restrict__ Wl2,
                                                    const float* __restrict__ Wr2,
                                                    unsigned short* __restrict__ wc1,
                                                    unsigned short* __restrict__ wc2) {
    int i = blockIdx.x * 256 + threadIdx.x;
    if (i < 64 * 128) {
        int oc = i >> 7, k = i & 127;
        float v = (k < 64) ? Wl1[oc * 64 + k] : Wr1[oc * 64 + k - 64];
        wc1[i] = f2b(v);
    } else if (i < 64 * 128 + 128 * 128) {
        int j = i - 64 * 128;
        int oc = j >> 7, k = j & 127;
        float v = (k < 64) ? Wl2[oc * 64 + k] : Wr2[oc * 64 + k - 64];
        wc2[j] = f2b(v);
    }
}

// ---------------- CSR build ----------------
__global__ __launch_bounds__(256) void deg_kernel(const int* __restrict__ dst,
                                                  int* __restrict__ degi, int E) {
    int e = blockIdx.x * 256 + threadIdx.x;
    if (e < E) atomicAdd(&degi[dst[e]], 1);
}

__global__ __launch_bounds__(1024) void scan_block_kernel(const int* __restrict__ degi,
                                                          int* __restrict__ rowptr,
                                                          int* __restrict__ bsum, int N) {
    __shared__ int tmp[1024];
    int tid = threadIdx.x;
    int i = blockIdx.x * 1024 + tid;
    int v = (i < N) ? degi[i] : 0;
    int val = v;
    tmp[tid] = v;
    __syncthreads();
    for (int off = 1; off < 1024; off <<= 1) {
        int t = (tid >= off) ? tmp[tid - off] : 0;
        __syncthreads();
        val += t;
        tmp[tid] = val;
        __syncthreads();
    }
    if (i < N) rowptr[i] = val - v;            // exclusive within block
    if (tid == 1023) bsum[blockIdx.x] = val;   // block total
}

__global__ __launch_bounds__(128) void scan_sums_kernel(int* __restrict__ bsum, int nb) {
    __shared__ int t[128];
    int tid = threadIdx.x;
    int v = (tid < nb) ? bsum[tid] : 0;
    int val = v;
    t[tid] = val;
    __syncthreads();
    for (int o = 1; o < 128; o <<= 1) {
        int add = (tid >= o) ? t[tid - o] : 0;
        __syncthreads();
        val += add;
        t[tid] = val;
        __syncthreads();
    }
    if (tid < nb) bsum[tid] = val - v;         // exclusive block offsets
}

__global__ __launch_bounds__(256) void scan_add_kernel(const int* __restrict__ bsum,
                                                       int* __restrict__ rowptr,
                                                       int* __restrict__ cursor,
                                                       int N, int E) {
    int i = blockIdx.x * 256 + threadIdx.x;
    if (i < N) {
        int r = rowptr[i] + bsum[i >> 10];
        rowptr[i] = r;
        cursor[i] = r;
    }
    if (i == N) rowptr[N] = E;
}

__global__ __launch_bounds__(256) void fill_kernel(const int* __restrict__ src,
                                                   const int* __restrict__ dst,
                                                   int* __restrict__ cursor,
                                                   int* __restrict__ csr, int E) {
    int e = blockIdx.x * 256 + threadIdx.x;
    if (e < E) {
        int pos = atomicAdd(&cursor[dst[e]], 1);
        csr[pos] = src[e];
    }
}

// ---------------- fused SAGE conv: 4-edge-parallel gather-mean + MFMA ----------------
// Block = 64 nodes, 4 waves (wave w owns nodes w*16..w*16+15 = its MFMA m-tile).
// Gather: lane = (edge-slot sg=lane>>4, feature-quad fq=lane&15); 4 edge rows
// fetched per load instruction, 2-deep unroll -> 8 rows in flight; shfl_xor
// butterfly reduces across slots. K=128: k<64 mean-agg (LDS), k>=64 self (global).
template <int OUTC, bool RELU, bool OUT_BF16>
__global__ __launch_bounds__(256) void sage_kernel(
    const unsigned short* __restrict__ featb,  // [N,64] bf16
    const int* __restrict__ csr,
    const int* __restrict__ rowptr,
    const unsigned short* __restrict__ wc,     // [OUTC,128] bf16
    const float* __restrict__ bias,            // [OUTC] f32
    void* __restrict__ outp,                   // bf16 [N,OUTC] or f32 [N,OUTC]
    int N) {
    constexpr int KP = 72;                     // 144B row = 9 x 16B slots
    constexpr int WP = 136;                    // 272B row = 17 x 16B slots
    __shared__ unsigned short feat[64 * KP];
    __shared__ unsigned short wt[OUTC * WP];

    const int tid = threadIdx.x, lane = tid & 63, w = tid >> 6;
    const int fq = lane & 15;                  // feature quad: features fq*4..fq*4+3
    const int sg = lane >> 4;                  // edge slot 0..3

    // stage weights, 16B chunks, coalesced
    for (int c = tid; c < OUTC * 16; c += 256) {
        int oc = c >> 4, k8 = (c & 15) * 8;
        *reinterpret_cast<uint4*>(&wt[oc * WP + k8]) =
            *reinterpret_cast<const uint4*>(&wc[oc * 128 + k8]);
    }

    // gather-mean: wave handles its 16 nodes, 4 edges at a time, 2-deep unrolled
    const int base = blockIdx.x * 64 + w * 16;
    for (int j = 0; j < 16; j++) {
        int node = base + j;
        int e0 = 0, e1 = 0;
        if (node < N) { e0 = rowptr[node]; e1 = rowptr[node + 1]; }
        float ax = 0.f, ay = 0.f, az = 0.f, aw = 0.f;
        int e = e0 + sg;
        for (; e + 4 < e1; e += 8) {           // 2 independent rows per lane-iter
            int s0 = csr[e], s1 = csr[e + 4];
            uint2 v0 = *reinterpret_cast<const uint2*>(&featb[(size_t)s0 * 64 + fq * 4]);
            uint2 v1 = *reinterpret_cast<const uint2*>(&featb[(size_t)s1 * 64 + fq * 4]);
            ax += __uint_as_float(v0.x << 16);
            ay += __uint_as_float(v0.x & 0xffff0000u);
            az += __uint_as_float(v0.y << 16);
            aw += __uint_as_float(v0.y & 0xffff0000u);
            ax += __uint_as_float(v1.x << 16);
            ay += __uint_as_float(v1.x & 0xffff0000u);
            az += __uint_as_float(v1.y << 16);
            aw += __uint_as_float(v1.y & 0xffff0000u);
        }
        if (e < e1) {
            int s0 = csr[e];
            uint2 v0 = *reinterpret_cast<const uint2*>(&featb[(size_t)s0 * 64 + fq * 4]);
            ax += __uint_as_float(v0.x << 16);
            ay += __uint_as_float(v0.x & 0xffff0000u);
            az += __uint_as_float(v0.y << 16);
            aw += __uint_as_float(v0.y & 0xffff0000u);
        }
        // butterfly-reduce across the 4 edge slots (lane bits 4,5)
        ax += __shfl_xor(ax, 16); ay += __shfl_xor(ay, 16);
        az += __shfl_xor(az, 16); aw += __shfl_xor(aw, 16);
        ax += __shfl_xor(ax, 32); ay += __shfl_xor(ay, 32);
        az += __shfl_xor(az, 32); aw += __shfl_xor(aw, 32);
        float inv = 1.0f / fmaxf((float)(e1 - e0), 1.0f);
        if (sg == 0) {
            unsigned int p0 = ((unsigned)f2b(ay * inv) << 16) | f2b(ax * inv);
            unsigned int p1 = ((unsigned)f2b(aw * inv) << 16) | f2b(az * inv);
            uint2 pk; pk.x = p0; pk.y = p1;
            *reinterpret_cast<uint2*>(&feat[(w * 16 + j) * KP + fq * 4]) = pk;
        }
    }
    __syncthreads();

    // MFMA phase
    const int hl = lane & 15, sgq = lane >> 4;
    bf16x8 a[4];
    a[0] = *reinterpret_cast<const bf16x8*>(&feat[(w * 16 + hl) * KP + sgq * 8]);
    a[1] = *reinterpret_cast<const bf16x8*>(&feat[(w * 16 + hl) * KP + 32 + sgq * 8]);
    int nclamp = min(base + hl, N - 1);
    const unsigned short* srow = &featb[(size_t)nclamp * 64];
    a[2] = *reinterpret_cast<const bf16x8*>(&srow[sgq * 8]);
    a[3] = *reinterpret_cast<const bf16x8*>(&srow[32 + sgq * 8]);

    constexpr int NT = OUTC / 16;
#pragma unroll
    for (int nt = 0; nt < NT; nt++) {
        f32x4 acc = {0.f, 0.f, 0.f, 0.f};
#pragma unroll
        for (int ks = 0; ks < 4; ks++) {
            bf16x8 b = *reinterpret_cast<const bf16x8*>(
                &wt[(nt * 16 + hl) * WP + ks * 32 + sgq * 8]);
            acc = __builtin_amdgcn_mfma_f32_16x16x32_bf16(a[ks], b, acc, 0, 0, 0);
        }
        float bv = bias[nt * 16 + hl];
#pragma unroll
        for (int r = 0; r < 4; r++) {
            int node = base + sgq * 4 + r;     // D row = (lane>>4)*4 + r
            if (node < N) {
                float v = acc[r] + bv;
                if (RELU) v = fmaxf(v, 0.f);
                int oc = nt * 16 + hl;         // D col = lane&15
                if (OUT_BF16)
                    ((unsigned short*)outp)[(size_t)node * OUTC + oc] = f2b(v);
                else
                    ((float*)outp)[(size_t)node * OUTC + oc] = v;
            }
        }
    }
}

// ---------------- segmented mean-pool over sorted batch ----------------
__global__ __launch_bounds__(128) void pool_kernel(const float* __restrict__ feat,   // [N,128]
                                                   const int* __restrict__ batch,
                                                   float* __restrict__ pooled,       // [G,128]
                                                   float* __restrict__ cnt,          // [G]
                                                   int n_nodes, int npb) {
    int o = threadIdx.x;
    int n0 = blockIdx.x * npb;
    if (n0 >= n_nodes) return;
    int n1 = min(n0 + npb, n_nodes);
    int cur = batch[n0];
    float acc = 0.f, c = 0.f;
    for (int n = n0; n < n1; n++) {
        int g = batch[n];
        if (g != cur) {
            atomicAdd(&pooled[cur * OUT_CH + o], acc);
            if (o == 0) atomicAdd(&cnt[cur], c);
            acc = 0.f; c = 0.f; cur = g;
        }
        acc += feat[(size_t)n * OUT_CH + o];
        c += 1.0f;
    }
    atomicAdd(&pooled[cur * OUT_CH + o], acc);
    if (o == 0) atomicAdd(&cnt[cur], c);
}

__global__ __launch_bounds__(256) void finalize_kernel(const float* __restrict__ pooled,
                                                       const float* __restrict__ cnt,
                                                       float* __restrict__ out, int total) {
    int t = blockIdx.x * 256 + threadIdx.x;
    if (t < total) out[t] = pooled[t] / fmaxf(cnt[t >> 7], 1.0f);
}

extern "C" void kernel_launch(void* const* d_in, const int* in_sizes, int n_in,
                              void* d_out, int out_size, void* d_ws, size_t ws_size,
                              hipStream_t stream) {
    const float* x    = (const float*)d_in[0];
    const int*   ei   = (const int*)d_in[1];
    const int*   bat  = (const int*)d_in[2];
    const float* Wl1  = (const float*)d_in[3];
    const float* Wr1  = (const float*)d_in[4];
    const float* b1   = (const float*)d_in[5];
    const float* Wl2  = (const float*)d_in[6];
    const float* Wr2  = (const float*)d_in[7];
    const float* b2   = (const float*)d_in[8];
    float* out = (float*)d_out;

    const int N = in_sizes[0] / IN_CH;        // 100000
    const int E = in_sizes[1] / 2;            // 1000000
    const int* srcp = ei;
    const int* dstp = ei + E;

    // workspace layout (256B aligned); total ~82 MB
    char* ws = (char*)d_ws;
    size_t off = 0;
    auto alloc = [&](size_t bytes) { size_t p = off; off += (bytes + 255) & ~255ull; return p; };
    size_t degi_off   = alloc((size_t)N * 4);               // zeroed; reused as cursor
    size_t cnt_off    = alloc((size_t)N_GRAPHS * 4);        // zeroed
    size_t pooled_off = alloc((size_t)N_GRAPHS * OUT_CH * 4); // zeroed
    size_t zero_end   = off;
    size_t xb_off     = alloc((size_t)N * 64 * 2);          // x in bf16
    size_t hb_off     = alloc((size_t)N * 64 * 2);          // h in bf16
    size_t out2_off   = alloc((size_t)N * OUT_CH * 4);      // conv2 out f32
    size_t rowptr_off = alloc((size_t)(N + 1) * 4);
    size_t bsum_off   = alloc(1024 * 4);
    size_t csr_off    = alloc((size_t)E * 4);
    size_t wc1_off    = alloc((size_t)64 * 128 * 2);
    size_t wc2_off    = alloc((size_t)128 * 128 * 2);
    (void)ws_size;

    int*            degi   = (int*)(ws + degi_off);
    float*          cnt    = (float*)(ws + cnt_off);
    float*          pooled = (float*)(ws + pooled_off);
    unsigned short* xb     = (unsigned short*)(ws + xb_off);
    unsigned short* hb     = (unsigned short*)(ws + hb_off);
    float*          out2   = (float*)(ws + out2_off);
    int*            rowptr = (int*)(ws + rowptr_off);
    int*            bsum   = (int*)(ws + bsum_off);
    int*            csr    = (int*)(ws + csr_off);
    unsigned short* wc1    = (unsigned short*)(ws + wc1_off);
    unsigned short* wc2    = (unsigned short*)(ws + wc2_off);
    int*            cursor = degi;   // degrees not needed after scan

    hipMemsetAsync(ws, 0, zero_end, stream);

    // prep: x->bf16, packed bf16 weights
    int n4 = N * 64 / 4;
    convert_kernel<<<(n4 + 255) / 256, 256, 0, stream>>>(x, xb, n4);
    wprep_kernel<<<(24576 + 255) / 256, 256, 0, stream>>>(Wl1, Wr1, Wl2, Wr2, wc1, wc2);

    // CSR build
    deg_kernel<<<(E + 255) / 256, 256, 0, stream>>>(dstp, degi, E);
    const int nb = (N + 1023) / 1024;
    scan_block_kernel<<<nb, 1024, 0, stream>>>(degi, rowptr, bsum, N);
    scan_sums_kernel<<<1, 128, 0, stream>>>(bsum, nb);
    scan_add_kernel<<<(N + 256) / 256, 256, 0, stream>>>(bsum, rowptr, cursor, N, E);
    fill_kernel<<<(E + 255) / 256, 256, 0, stream>>>(srcp, dstp, cursor, csr, E);

    // fused convs
    const int nblk = (N + 63) / 64;
    sage_kernel<64, true, true><<<nblk, 256, 0, stream>>>(xb, csr, rowptr, wc1, b1, hb, N);
    sage_kernel<128, false, false><<<nblk, 256, 0, stream>>>(hb, csr, rowptr, wc2, b2, out2, N);

    // global mean pool
    const int npb = 64;
    pool_kernel<<<(N + npb - 1) / npb, 128, 0, stream>>>(out2, bat, pooled, cnt, N, npb);
    finalize_kernel<<<(N_GRAPHS * OUT_CH + 255) / 256, 256, 0, stream>>>(
        pooled, cnt, out, N_GRAPHS * OUT_CH);
}